// Round 3
// baseline (1557.063 us; speedup 1.0000x reference)
//
#include <hip/hip_runtime.h>

typedef _Float16 half8 __attribute__((ext_vector_type(8)));
typedef float f32x4 __attribute__((ext_vector_type(4)));

#define TSIZE (1 << 19)
#define TMASK (TSIZE - 1)

// floor(32 * 1.3819^l) for l=0..15, computed in extended precision; every value
// is >=0.03 away from an integer so fp32-pow 1-ulp differences cannot flip floor.
__constant__ int c_res[16] = {32, 44, 61, 84, 116, 161, 222, 307,
                              425, 588, 812, 1123, 1551, 2144, 2963, 4095};

__global__ void hg_cvt_f32_f16(const float* __restrict__ s, _Float16* __restrict__ d, int n) {
  int stride = gridDim.x * blockDim.x;
  for (int i = blockIdx.x * blockDim.x + threadIdx.x; i < n; i += stride)
    d[i] = (_Float16)s[i];
}

// deg-9 Taylor: |err| < 3e-8 for |x|<=1; all |h| here are < ~0.5 (guarded fallback).
__device__ __forceinline__ float fast_sin(float x) {
  if (__builtin_expect(fabsf(x) > 1.0f, 0)) return sinf(x);
  float x2 = x * x;
  float p = 2.75573192e-6f;
  p = fmaf(p, x2, -1.98412698e-4f);
  p = fmaf(p, x2, 8.33333333e-3f);
  p = fmaf(p, x2, -1.66666667e-1f);
  return fmaf(p * x2, x, x);
}

// LDS: X tile [64 pts][64 feats] f16 at 0 (8 KB), S tile [64][512] f16 at 8192 (64 KB).
// XOR swizzle (row&7)<<4 on the byte offset breaks the 16-way bank conflict of
// power-of-2 row strides on ds_read_b128 (guide §6 G4). Same XOR on read & write.
#define LD_X(m, k) (*(const half8*)(&smem[(m) * 128 + (((k) * 2) ^ (((m) & 7) << 4))]))
#define LD_S(m, k) (*(const half8*)(&smem[8192 + (m) * 1024 + (((k) * 2) ^ (((m) & 7) << 4))]))
#define ST_S(m, n, v)                                                                   \
  do {                                                                                  \
    *(_Float16*)(&smem[8192 + (m) * 1024 + (((n) * 2) ^ (((m) & 7) << 4))]) = (v);      \
  } while (0)

__global__ void __launch_bounds__(512)
hg_fused(const int* __restrict__ ybuf, const int* __restrict__ xbuf,
         const float* __restrict__ cam, const float* __restrict__ table,
         const _Float16* __restrict__ W1h, const float* __restrict__ b1,
         const _Float16* __restrict__ W2h, const float* __restrict__ b2,
         const _Float16* __restrict__ W3h, const float* __restrict__ b3,
         float* __restrict__ out) {
  __shared__ __align__(16) unsigned char smem[73728];
  const int t = threadIdx.x;
  const int lane = t & 63;
  const int wid = t >> 6;   // 8 waves
  const int l15 = lane & 15;
  const int lhi = lane >> 4;
  const int pbase = blockIdx.x << 6;  // 64 points per block
  const f32x4 vzero = {0.f, 0.f, 0.f, 0.f};

  // ---------------- hashgrid encode -> X_lds[64][64] f16 ----------------
  {
    const int m = t >> 3;    // local point 0..63
    const int sub = t & 7;   // handles levels sub, sub+8 and cam cols 4*sub..4*sub+3
    const int p = pbase + m;
    const float u = (float)xbuf[p] / 511.0f;  // uv[:,0] from x
    const float v = (float)ybuf[p] / 511.0f;  // uv[:,1] from y
    const int swz = (m & 7) << 4;
#pragma unroll
    for (int hh = 0; hh < 2; ++hh) {
      const int l = sub + hh * 8;
      const int res = c_res[l];
      const float rf = (float)res;
      const float px = u * rf, py = v * rf;
      int p0x = (int)floorf(px); p0x = p0x < 0 ? 0 : (p0x > res - 1 ? res - 1 : p0x);
      int p0y = (int)floorf(py); p0y = p0y < 0 ? 0 : (p0y > res - 1 ? res - 1 : p0y);
      const float fx = px - (float)p0x, fy = py - (float)p0y;
      const unsigned strd = (unsigned)(res + 1);
      const bool dense = (res <= 723);  // (res+1)^2 <= 2^19
      const float* tb = table + ((size_t)l * TSIZE) * 2;
      const float w00 = (1.f - fx) * (1.f - fy), w10 = fx * (1.f - fy);
      const float w01 = (1.f - fx) * fy, w11 = fx * fy;
      float c0 = 0.f, c1 = 0.f;
#pragma unroll
      for (int c = 0; c < 4; ++c) {
        const unsigned cx = (unsigned)(p0x + (c & 1));
        const unsigned cy = (unsigned)(p0y + (c >> 1));
        const unsigned idx = dense ? (cx + cy * strd)
                                   : ((cx ^ (cy * 2654435761u)) & TMASK);
        const float2 f = *(const float2*)(tb + (size_t)idx * 2);
        const float w = (c == 0) ? w00 : (c == 1) ? w10 : (c == 2) ? w01 : w11;
        c0 = fmaf(w, f.x, c0);
        c1 = fmaf(w, f.y, c1);
      }
      _Float16* dst = (_Float16*)&smem[m * 128 + ((4 * l) ^ swz)];
      dst[0] = (_Float16)c0;
      dst[1] = (_Float16)c1;
    }
    const float4 cf = ((const float4*)cam)[sub];
    _Float16* dc = (_Float16*)&smem[m * 128 + ((64 + 8 * sub) ^ swz)];
    dc[0] = (_Float16)cf.x; dc[1] = (_Float16)cf.y;
    dc[2] = (_Float16)cf.z; dc[3] = (_Float16)cf.w;
  }
  __syncthreads();

  // ---------------- L1: X[64,64] @ W1^T -> sin -> S[64,512] ----------------
  {
    const int n0 = wid << 6;
    f32x4 acc[4][4];
#pragma unroll
    for (int i = 0; i < 4; ++i)
#pragma unroll
      for (int j = 0; j < 4; ++j) acc[i][j] = vzero;
#pragma unroll
    for (int ks = 0; ks < 2; ++ks) {
      const int kk = ks * 32 + lhi * 8;
      half8 b[4];
#pragma unroll
      for (int nf = 0; nf < 4; ++nf)
        b[nf] = *(const half8*)(W1h + (size_t)(n0 + nf * 16 + l15) * 64 + kk);
      half8 a[4];
#pragma unroll
      for (int mf = 0; mf < 4; ++mf) a[mf] = LD_X(mf * 16 + l15, kk);
#pragma unroll
      for (int mf = 0; mf < 4; ++mf)
#pragma unroll
        for (int nf = 0; nf < 4; ++nf)
          acc[mf][nf] = __builtin_amdgcn_mfma_f32_16x16x32_f16(a[mf], b[nf], acc[mf][nf], 0, 0, 0);
    }
#pragma unroll
    for (int nf = 0; nf < 4; ++nf) {
      const float bb = b1[n0 + nf * 16 + l15];
#pragma unroll
      for (int mf = 0; mf < 4; ++mf)
#pragma unroll
        for (int r = 0; r < 4; ++r) {
          float h = acc[mf][nf][r] + bb;
          h = fminf(fmaxf(h, -25.133f), 25.133f);
          ST_S(mf * 16 + lhi * 4 + r, n0 + nf * 16 + l15, (_Float16)fast_sin(h));
        }
    }
  }
  __syncthreads();

  // ---------------- L2: S[64,512] @ W2^T -> sin -> S (in place after barrier) ----
  {
    const int n0 = wid << 6;
    f32x4 acc[4][4];
#pragma unroll
    for (int i = 0; i < 4; ++i)
#pragma unroll
      for (int j = 0; j < 4; ++j) acc[i][j] = vzero;
#pragma unroll 2
    for (int ks = 0; ks < 16; ++ks) {
      const int kk = ks * 32 + lhi * 8;
      half8 b[4];
#pragma unroll
      for (int nf = 0; nf < 4; ++nf)
        b[nf] = *(const half8*)(W2h + (size_t)(n0 + nf * 16 + l15) * 512 + kk);
      half8 a[4];
#pragma unroll
      for (int mf = 0; mf < 4; ++mf) a[mf] = LD_S(mf * 16 + l15, kk);
#pragma unroll
      for (int mf = 0; mf < 4; ++mf)
#pragma unroll
        for (int nf = 0; nf < 4; ++nf)
          acc[mf][nf] = __builtin_amdgcn_mfma_f32_16x16x32_f16(a[mf], b[nf], acc[mf][nf], 0, 0, 0);
    }
    __syncthreads();  // all waves finished reading S1 before overwrite
#pragma unroll
    for (int nf = 0; nf < 4; ++nf) {
      const float bb = b2[n0 + nf * 16 + l15];
#pragma unroll
      for (int mf = 0; mf < 4; ++mf)
#pragma unroll
        for (int r = 0; r < 4; ++r) {
          float h = acc[mf][nf][r] + bb;
          h = fminf(fmaxf(h, -25.133f), 25.133f);
          ST_S(mf * 16 + lhi * 4 + r, n0 + nf * 16 + l15, (_Float16)fast_sin(h));
        }
    }
  }
  __syncthreads();

  // ---------------- L3: S[64,512] @ W3^T -> sin -> out[64,384] fp32 ----------------
  {
    const int n0 = wid * 48;
    f32x4 acc[4][3];
#pragma unroll
    for (int i = 0; i < 4; ++i)
#pragma unroll
      for (int j = 0; j < 3; ++j) acc[i][j] = vzero;
#pragma unroll 2
    for (int ks = 0; ks < 16; ++ks) {
      const int kk = ks * 32 + lhi * 8;
      half8 b[3];
#pragma unroll
      for (int nf = 0; nf < 3; ++nf)
        b[nf] = *(const half8*)(W3h + (size_t)(n0 + nf * 16 + l15) * 512 + kk);
      half8 a[4];
#pragma unroll
      for (int mf = 0; mf < 4; ++mf) a[mf] = LD_S(mf * 16 + l15, kk);
#pragma unroll
      for (int mf = 0; mf < 4; ++mf)
#pragma unroll
        for (int nf = 0; nf < 3; ++nf)
          acc[mf][nf] = __builtin_amdgcn_mfma_f32_16x16x32_f16(a[mf], b[nf], acc[mf][nf], 0, 0, 0);
    }
#pragma unroll
    for (int nf = 0; nf < 3; ++nf) {
      const float bb = b3[n0 + nf * 16 + l15];
#pragma unroll
      for (int mf = 0; mf < 4; ++mf)
#pragma unroll
        for (int r = 0; r < 4; ++r) {
          float h = acc[mf][nf][r] + bb;
          h = fminf(fmaxf(h, -25.133f), 25.133f);
          out[(size_t)(pbase + mf * 16 + lhi * 4 + r) * 384 + (n0 + nf * 16 + l15)] =
              fast_sin(h);
        }
    }
  }
}

extern "C" void kernel_launch(void* const* d_in, const int* in_sizes, int n_in,
                              void* d_out, int out_size, void* d_ws, size_t ws_size,
                              hipStream_t stream) {
  const int* y = (const int*)d_in[0];
  const int* x = (const int*)d_in[1];
  const float* cam = (const float*)d_in[2];
  const float* table = (const float*)d_in[3];
  const float* W1 = (const float*)d_in[4];
  const float* b1 = (const float*)d_in[5];
  const float* W2 = (const float*)d_in[6];
  const float* b2 = (const float*)d_in[7];
  const float* W3 = (const float*)d_in[8];
  const float* b3 = (const float*)d_in[9];
  float* out = (float*)d_out;

  // fp16 weight copies in workspace: 983,040 B total
  _Float16* W1h = (_Float16*)d_ws;            // 512*64
  _Float16* W2h = W1h + 512 * 64;             // 512*512
  _Float16* W3h = W2h + 512 * 512;            // 384*512

  hg_cvt_f32_f16<<<128, 256, 0, stream>>>(W1, W1h, 512 * 64);
  hg_cvt_f32_f16<<<512, 256, 0, stream>>>(W2, W2h, 512 * 512);
  hg_cvt_f32_f16<<<512, 256, 0, stream>>>(W3, W3h, 384 * 512);

  const int nblocks = (1 << 19) / 64;  // 8192
  hg_fused<<<nblocks, 512, 0, stream>>>(y, x, cam, table, W1h, b1, W2h, b2, W3h, b3, out);
}

// Round 4
// 1526.436 us; speedup vs baseline: 1.0201x; 1.0201x over previous
//
#include <hip/hip_runtime.h>

typedef _Float16 half8 __attribute__((ext_vector_type(8)));
typedef _Float16 half4 __attribute__((ext_vector_type(4)));
typedef _Float16 half2v __attribute__((ext_vector_type(2)));
typedef float f32x4 __attribute__((ext_vector_type(4)));

#define TSIZE (1 << 19)
#define TMASK (TSIZE - 1)

// floor(32 * 1.3819^l) for l=0..15; every value >=0.03 from an integer.
__constant__ int c_res[16] = {32, 44, 61, 84, 116, 161, 222, 307,
                              425, 588, 812, 1123, 1551, 2144, 2963, 4095};

// Fused f32->f16 weight conversion (one launch). Segments: W1 32768, W2 262144, W3 196608.
__global__ void hg_cvt_all(const float* __restrict__ W1, const float* __restrict__ W2,
                           const float* __restrict__ W3, _Float16* __restrict__ d) {
  int g = blockIdx.x * blockDim.x + threadIdx.x;  // 122880 groups of 4
  int i = g * 4;
  const float* s;
  if (i < 32768) s = W1 + i;
  else if (i < 32768 + 262144) s = W2 + (i - 32768);
  else s = W3 + (i - 32768 - 262144);
  float4 v = *(const float4*)s;
  half4 h = {(_Float16)v.x, (_Float16)v.y, (_Float16)v.z, (_Float16)v.w};
  *(half4*)(d + i) = h;
}

// deg-9 Taylor: |err| < 3e-8 for |x|<=1; guarded fallback (|h| here ~<0.5).
__device__ __forceinline__ float fast_sin(float x) {
  if (__builtin_expect(fabsf(x) > 1.0f, 0)) return sinf(x);
  float x2 = x * x;
  float p = 2.75573192e-6f;
  p = fmaf(p, x2, -1.98412698e-4f);
  p = fmaf(p, x2, 8.33333333e-3f);
  p = fmaf(p, x2, -1.66666667e-1f);
  return fmaf(p * x2, x, x);
}

// LDS: X [64 pts][64 feats] f16 at 0 (8 KB), S [64 pts][512] f16 at 8192 (64 KB).
// XOR swizzle (row&7)<<4 breaks the 16/32-way bank conflict of power-of-2 row
// strides on ds_read_b128 (guide §6 G4). Same XOR on read & write.
#define LD_X(m, k) (*(const half8*)(&smem[(m) * 128 + (((k) * 2) ^ (((m) & 7) << 4))]))
#define LD_S(m, k) (*(const half8*)(&smem[8192 + (m) * 1024 + (((k) * 2) ^ (((m) & 7) << 4))]))
// packed 8B store of 4 consecutive f16 cols (n multiple of 4)
#define ST_S8(m, n, v)                                                                  \
  do {                                                                                  \
    *(half4*)(&smem[8192 + (m) * 1024 + (((n) * 2) ^ (((m) & 7) << 4))]) = (v);         \
  } while (0)

__global__ void __launch_bounds__(1024, 8)
hg_fused(const int* __restrict__ ybuf, const int* __restrict__ xbuf,
         const float* __restrict__ cam, const float* __restrict__ table,
         const _Float16* __restrict__ W1h, const float* __restrict__ b1,
         const _Float16* __restrict__ W2h, const float* __restrict__ b2,
         const _Float16* __restrict__ W3h, const float* __restrict__ b3,
         float* __restrict__ out) {
  __shared__ __align__(16) unsigned char smem[73728];
  const int t = threadIdx.x;
  const int lane = t & 63;
  const int wid = t >> 6;   // 16 waves
  const int l15 = lane & 15;
  const int lhi = lane >> 4;
  const int pbase = blockIdx.x << 6;  // 64 points per block
  const f32x4 vzero = {0.f, 0.f, 0.f, 0.f};

  // ---------------- hashgrid encode -> X_lds[64][64] f16 ----------------
  {
    const int m = t >> 4;    // local point 0..63
    const int sub = t & 15;  // level index; also cam pair index
    const int p = pbase + m;
    const float u = (float)xbuf[p] / 511.0f;
    const float v = (float)ybuf[p] / 511.0f;
    const int swz = (m & 7) << 4;

    const int res = c_res[sub];
    const float rf = (float)res;
    const float px = u * rf, py = v * rf;
    int p0x = (int)floorf(px); p0x = p0x < 0 ? 0 : (p0x > res - 1 ? res - 1 : p0x);
    int p0y = (int)floorf(py); p0y = p0y < 0 ? 0 : (p0y > res - 1 ? res - 1 : p0y);
    const float fx = px - (float)p0x, fy = py - (float)p0y;
    const unsigned strd = (unsigned)(res + 1);
    const bool dense = (res <= 723);  // (res+1)^2 <= 2^19
    const float* tb = table + ((size_t)sub * TSIZE) * 2;
    const float w00 = (1.f - fx) * (1.f - fy), w10 = fx * (1.f - fy);
    const float w01 = (1.f - fx) * fy, w11 = fx * fy;
    float c0 = 0.f, c1 = 0.f;
#pragma unroll
    for (int c = 0; c < 4; ++c) {
      const unsigned cx = (unsigned)(p0x + (c & 1));
      const unsigned cy = (unsigned)(p0y + (c >> 1));
      const unsigned idx = dense ? (cx + cy * strd)
                                 : ((cx ^ (cy * 2654435761u)) & TMASK);
      const float2 f = *(const float2*)(tb + (size_t)idx * 2);
      const float w = (c == 0) ? w00 : (c == 1) ? w10 : (c == 2) ? w01 : w11;
      c0 = fmaf(w, f.x, c0);
      c1 = fmaf(w, f.y, c1);
    }
    half2v hf = {(_Float16)c0, (_Float16)c1};
    *(half2v*)(&smem[m * 128 + ((4 * sub) ^ swz)]) = hf;

    const float2 cf = ((const float2*)cam)[sub];
    half2v hc = {(_Float16)cf.x, (_Float16)cf.y};
    *(half2v*)(&smem[m * 128 + ((64 + 4 * sub) ^ swz)]) = hc;
  }
  __syncthreads();

  // ---------------- L1: sin(X @ W1^T + b1) -> S[64,512] ----------------
  // Operand swap: mfma(A=W_frag, B=X_frag) => C[row=n local][col=point].
  // Thread holds 4 CONSECUTIVE n (lhi*4+r) for point l15 -> packed epilogue.
  {
    const int n0 = wid << 5;  // 32 cols per wave
    f32x4 acc[4][2];
#pragma unroll
    for (int i = 0; i < 4; ++i) { acc[i][0] = vzero; acc[i][1] = vzero; }
#pragma unroll
    for (int ks = 0; ks < 2; ++ks) {
      const int kk = ks * 32 + lhi * 8;
      half8 bw[2];
#pragma unroll
      for (int nf = 0; nf < 2; ++nf)
        bw[nf] = *(const half8*)(W1h + (n0 + nf * 16 + l15) * 64 + kk);
      half8 ax[4];
#pragma unroll
      for (int mf = 0; mf < 4; ++mf) ax[mf] = LD_X(mf * 16 + l15, kk);
#pragma unroll
      for (int mf = 0; mf < 4; ++mf)
#pragma unroll
        for (int nf = 0; nf < 2; ++nf)
          acc[mf][nf] = __builtin_amdgcn_mfma_f32_16x16x32_f16(bw[nf], ax[mf], acc[mf][nf], 0, 0, 0);
    }
#pragma unroll
    for (int nf = 0; nf < 2; ++nf) {
      const int nb = n0 + nf * 16 + lhi * 4;
      const f32x4 bb = *(const f32x4*)(b1 + nb);
#pragma unroll
      for (int mf = 0; mf < 4; ++mf) {
        half4 pk;
#pragma unroll
        for (int r = 0; r < 4; ++r) {
          float h = acc[mf][nf][r] + bb[r];
          h = fminf(fmaxf(h, -25.133f), 25.133f);
          pk[r] = (_Float16)fast_sin(h);
        }
        ST_S8(mf * 16 + l15, nb, pk);
      }
    }
  }
  __syncthreads();

  // ---------------- L2: sin(S @ W2^T + b2) -> S (in place, after barrier) ----
  {
    const int n0 = wid << 5;
    f32x4 acc[4][2];
#pragma unroll
    for (int i = 0; i < 4; ++i) { acc[i][0] = vzero; acc[i][1] = vzero; }
    for (int ks = 0; ks < 16; ++ks) {
      const int kk = ks * 32 + lhi * 8;
      half8 bw[2];
#pragma unroll
      for (int nf = 0; nf < 2; ++nf)
        bw[nf] = *(const half8*)(W2h + (n0 + nf * 16 + l15) * 512 + kk);
      half8 ax[4];
#pragma unroll
      for (int mf = 0; mf < 4; ++mf) ax[mf] = LD_S(mf * 16 + l15, kk);
#pragma unroll
      for (int mf = 0; mf < 4; ++mf)
#pragma unroll
        for (int nf = 0; nf < 2; ++nf)
          acc[mf][nf] = __builtin_amdgcn_mfma_f32_16x16x32_f16(bw[nf], ax[mf], acc[mf][nf], 0, 0, 0);
    }
    __syncthreads();  // all waves done READING S1 before overwrite
#pragma unroll
    for (int nf = 0; nf < 2; ++nf) {
      const int nb = n0 + nf * 16 + lhi * 4;
      const f32x4 bb = *(const f32x4*)(b2 + nb);
#pragma unroll
      for (int mf = 0; mf < 4; ++mf) {
        half4 pk;
#pragma unroll
        for (int r = 0; r < 4; ++r) {
          float h = acc[mf][nf][r] + bb[r];
          h = fminf(fmaxf(h, -25.133f), 25.133f);
          pk[r] = (_Float16)fast_sin(h);
        }
        ST_S8(mf * 16 + l15, nb, pk);
      }
    }
  }
  __syncthreads();

  // ---------------- L3: sin(S @ W3^T + b3) -> out[64,384] fp32 ----------------
  // 24 col-tiles over 16 waves: all waves take tile wid; waves 0-7 also 16+wid.
  {
    const int c0 = wid << 4;
    const int c1 = 256 + (wid << 4);
    const bool two = (wid < 8);
    f32x4 acc0[4], acc1[4];
#pragma unroll
    for (int i = 0; i < 4; ++i) { acc0[i] = vzero; acc1[i] = vzero; }
    for (int ks = 0; ks < 16; ++ks) {
      const int kk = ks * 32 + lhi * 8;
      const half8 bw0 = *(const half8*)(W3h + (c0 + l15) * 512 + kk);
      half8 bw1;
      if (two) bw1 = *(const half8*)(W3h + (c1 + l15) * 512 + kk);
      half8 ax[4];
#pragma unroll
      for (int mf = 0; mf < 4; ++mf) ax[mf] = LD_S(mf * 16 + l15, kk);
#pragma unroll
      for (int mf = 0; mf < 4; ++mf)
        acc0[mf] = __builtin_amdgcn_mfma_f32_16x16x32_f16(bw0, ax[mf], acc0[mf], 0, 0, 0);
      if (two) {
#pragma unroll
        for (int mf = 0; mf < 4; ++mf)
          acc1[mf] = __builtin_amdgcn_mfma_f32_16x16x32_f16(bw1, ax[mf], acc1[mf], 0, 0, 0);
      }
    }
    {
      const int nb = c0 + lhi * 4;
      const f32x4 bb = *(const f32x4*)(b3 + nb);
#pragma unroll
      for (int mf = 0; mf < 4; ++mf) {
        float4 o;
        float* op = &o.x;
#pragma unroll
        for (int r = 0; r < 4; ++r) {
          float h = acc0[mf][r] + bb[r];
          h = fminf(fmaxf(h, -25.133f), 25.133f);
          op[r] = fast_sin(h);
        }
        *(float4*)(out + (size_t)(pbase + mf * 16 + l15) * 384 + nb) = o;
      }
    }
    if (two) {
      const int nb = c1 + lhi * 4;
      const f32x4 bb = *(const f32x4*)(b3 + nb);
#pragma unroll
      for (int mf = 0; mf < 4; ++mf) {
        float4 o;
        float* op = &o.x;
#pragma unroll
        for (int r = 0; r < 4; ++r) {
          float h = acc1[mf][r] + bb[r];
          h = fminf(fmaxf(h, -25.133f), 25.133f);
          op[r] = fast_sin(h);
        }
        *(float4*)(out + (size_t)(pbase + mf * 16 + l15) * 384 + nb) = o;
      }
    }
  }
}

extern "C" void kernel_launch(void* const* d_in, const int* in_sizes, int n_in,
                              void* d_out, int out_size, void* d_ws, size_t ws_size,
                              hipStream_t stream) {
  const int* y = (const int*)d_in[0];
  const int* x = (const int*)d_in[1];
  const float* cam = (const float*)d_in[2];
  const float* table = (const float*)d_in[3];
  const float* W1 = (const float*)d_in[4];
  const float* b1 = (const float*)d_in[5];
  const float* W2 = (const float*)d_in[6];
  const float* b2 = (const float*)d_in[7];
  const float* W3 = (const float*)d_in[8];
  const float* b3 = (const float*)d_in[9];
  float* out = (float*)d_out;

  _Float16* Wh = (_Float16*)d_ws;      // W1h | W2h | W3h contiguous, 983040 B
  _Float16* W1h = Wh;                  // 512*64
  _Float16* W2h = W1h + 512 * 64;      // 512*512
  _Float16* W3h = W2h + 512 * 512;     // 384*512

  hg_cvt_all<<<480, 256, 0, stream>>>(W1, W2, W3, Wh);

  const int nblocks = (1 << 19) / 64;  // 8192
  hg_fused<<<nblocks, 1024, 0, stream>>>(y, x, cam, table, W1h, b1, W2h, b2, W3h, b3, out);
}

// Round 5
// 1142.470 us; speedup vs baseline: 1.3629x; 1.3361x over previous
//
#include <hip/hip_runtime.h>

typedef _Float16 half8 __attribute__((ext_vector_type(8)));
typedef _Float16 half4 __attribute__((ext_vector_type(4)));
typedef _Float16 half2v __attribute__((ext_vector_type(2)));
typedef float f32x4 __attribute__((ext_vector_type(4)));

#define TSIZE (1 << 19)
#define TMASK (TSIZE - 1)

// floor(32 * 1.3819^l) for l=0..15; every value >=0.03 from an integer.
__constant__ int c_res[16] = {32, 44, 61, 84, 116, 161, 222, 307,
                              425, 588, 812, 1123, 1551, 2144, 2963, 4095};

// Fused f32->f16 weight conversion. Segments: W1 32768, W2 262144, W3 196608 elems.
__global__ void hg_cvt_all(const float* __restrict__ W1, const float* __restrict__ W2,
                           const float* __restrict__ W3, _Float16* __restrict__ d) {
  int g = blockIdx.x * blockDim.x + threadIdx.x;  // 122880 groups of 4
  int i = g * 4;
  const float* s;
  if (i < 32768) s = W1 + i;
  else if (i < 32768 + 262144) s = W2 + (i - 32768);
  else s = W3 + (i - 32768 - 262144);
  float4 v = *(const float4*)s;
  half4 h = {(_Float16)v.x, (_Float16)v.y, (_Float16)v.z, (_Float16)v.w};
  *(half4*)(d + i) = h;
}

// deg-9 Taylor: |err| < 3e-8 for |x|<=1; guarded fallback (|h| here ~<0.5).
__device__ __forceinline__ float fast_sin(float x) {
  if (__builtin_expect(fabsf(x) > 1.0f, 0)) return sinf(x);
  float x2 = x * x;
  float p = 2.75573192e-6f;
  p = fmaf(p, x2, -1.98412698e-4f);
  p = fmaf(p, x2, 8.33333333e-3f);
  p = fmaf(p, x2, -1.66666667e-1f);
  return fmaf(p * x2, x, x);
}

// LDS: X [128 pts][64 f16] at 0 (16 KB), S [128 pts][512 f16] at 16384 (128 KB).
// XOR swizzle (row&7)<<4 breaks power-of-2-stride bank conflicts on ds_read_b128
// (guide §6 G4); same XOR on read & write.
#define LD_X(m, k) (*(const half8*)(&smem[(m) * 128 + (((k) * 2) ^ (((m) & 7) << 4))]))
#define LD_S(m, k) \
  (*(const half8*)(&smem[16384 + (m) * 1024 + (((k) * 2) ^ (((m) & 7) << 4))]))
#define ST_S8(m, n, v)                                                                  \
  do {                                                                                  \
    *(half4*)(&smem[16384 + (m) * 1024 + (((n) * 2) ^ (((m) & 7) << 4))]) = (v);        \
  } while (0)

#define MFMA16 __builtin_amdgcn_mfma_f32_16x16x32_f16

__global__ void __launch_bounds__(1024, 4)  // VGPR cap 128: 1 block/CU, no spill
hg_fused(const int* __restrict__ ybuf, const int* __restrict__ xbuf,
         const float* __restrict__ cam, const float* __restrict__ table,
         const _Float16* __restrict__ W1h, const float* __restrict__ b1,
         const _Float16* __restrict__ W2h, const float* __restrict__ b2,
         const _Float16* __restrict__ W3h, const float* __restrict__ b3,
         float* __restrict__ out) {
  __shared__ __align__(16) unsigned char smem[147456];
  const int t = threadIdx.x;
  const int lane = t & 63;
  const int wid = t >> 6;   // 16 waves
  const int l15 = lane & 15;
  const int lhi = lane >> 4;
  const int pbase = blockIdx.x << 7;  // 128 points per block
  const f32x4 vzero = {0.f, 0.f, 0.f, 0.f};

  // ---------------- hashgrid encode -> X_lds[128][64] f16 ----------------
  {
    const int sub = t & 15;  // level index; also cam pair index
    const int res = c_res[sub];
    const float rf = (float)res;
    const unsigned strd = (unsigned)(res + 1);
    const bool dense = (res <= 723);  // (res+1)^2 <= 2^19
    const float* tb = table + ((size_t)sub * TSIZE) * 2;
    const float2 cf = ((const float2*)cam)[sub];
    const half2v hc = {(_Float16)cf.x, (_Float16)cf.y};
#pragma unroll
    for (int hh = 0; hh < 2; ++hh) {
      const int m = (t >> 4) + hh * 64;  // local point 0..127
      const int p = pbase + m;
      const float u = (float)xbuf[p] / 511.0f;
      const float v = (float)ybuf[p] / 511.0f;
      const int swz = (m & 7) << 4;
      const float px = u * rf, py = v * rf;
      int p0x = (int)floorf(px); p0x = p0x < 0 ? 0 : (p0x > res - 1 ? res - 1 : p0x);
      int p0y = (int)floorf(py); p0y = p0y < 0 ? 0 : (p0y > res - 1 ? res - 1 : p0y);
      const float fx = px - (float)p0x, fy = py - (float)p0y;
      const float w00 = (1.f - fx) * (1.f - fy), w10 = fx * (1.f - fy);
      const float w01 = (1.f - fx) * fy, w11 = fx * fy;
      float c0 = 0.f, c1 = 0.f;
#pragma unroll
      for (int c = 0; c < 4; ++c) {
        const unsigned cx = (unsigned)(p0x + (c & 1));
        const unsigned cy = (unsigned)(p0y + (c >> 1));
        const unsigned idx = dense ? (cx + cy * strd)
                                   : ((cx ^ (cy * 2654435761u)) & TMASK);
        const float2 f = *(const float2*)(tb + (size_t)idx * 2);
        const float w = (c == 0) ? w00 : (c == 1) ? w10 : (c == 2) ? w01 : w11;
        c0 = fmaf(w, f.x, c0);
        c1 = fmaf(w, f.y, c1);
      }
      half2v hf = {(_Float16)c0, (_Float16)c1};
      *(half2v*)(&smem[m * 128 + ((4 * sub) ^ swz)]) = hf;
      *(half2v*)(&smem[m * 128 + ((64 + 4 * sub) ^ swz)]) = hc;
    }
  }
  __syncthreads();

  // ---------------- L1: sin(X @ W1^T + b1) -> S[128,512] ----------------
  // Swapped operands: mfma(A=W_frag, B=X_frag) => C[row=n][col=point];
  // thread holds 4 consecutive n for one point -> packed 8B epilogue stores.
  {
    const int n0 = wid << 5;  // 32 cols/wave
    f32x4 acc[8][2];
#pragma unroll
    for (int i = 0; i < 8; ++i) { acc[i][0] = vzero; acc[i][1] = vzero; }
#pragma unroll
    for (int ks = 0; ks < 2; ++ks) {
      const int kk = ks * 32 + lhi * 8;
      const half8 bw0 = *(const half8*)(W1h + (n0 + l15) * 64 + kk);
      const half8 bw1 = *(const half8*)(W1h + (n0 + 16 + l15) * 64 + kk);
#pragma unroll
      for (int mh = 0; mh < 2; ++mh) {
        half8 ax[4];
#pragma unroll
        for (int q = 0; q < 4; ++q) ax[q] = LD_X((mh * 4 + q) * 16 + l15, kk);
#pragma unroll
        for (int q = 0; q < 4; ++q) {
          acc[mh * 4 + q][0] = MFMA16(bw0, ax[q], acc[mh * 4 + q][0], 0, 0, 0);
          acc[mh * 4 + q][1] = MFMA16(bw1, ax[q], acc[mh * 4 + q][1], 0, 0, 0);
        }
      }
    }
#pragma unroll
    for (int nf = 0; nf < 2; ++nf) {
      const int nb = n0 + nf * 16 + lhi * 4;
      const f32x4 bb = *(const f32x4*)(b1 + nb);
#pragma unroll
      for (int mf = 0; mf < 8; ++mf) {
        half4 pk;
#pragma unroll
        for (int r = 0; r < 4; ++r) {
          float h = acc[mf][nf][r] + bb[r];
          h = fminf(fmaxf(h, -25.133f), 25.133f);
          pk[r] = (_Float16)fast_sin(h);
        }
        ST_S8(mf * 16 + l15, nb, pk);
      }
    }
  }
  __syncthreads();

  // ---------------- L2: sin(S @ W2^T + b2) -> S (in place after barrier) ----
  {
    const int n0 = wid << 5;
    f32x4 acc[8][2];
#pragma unroll
    for (int i = 0; i < 8; ++i) { acc[i][0] = vzero; acc[i][1] = vzero; }
    // software-pipelined W prefetch: load ks+1's B-fragments before ks's MFMAs
    half8 bw0 = *(const half8*)(W2h + (n0 + l15) * 512 + lhi * 8);
    half8 bw1 = *(const half8*)(W2h + (n0 + 16 + l15) * 512 + lhi * 8);
#pragma unroll 2
    for (int ks = 0; ks < 16; ++ks) {
      const int kkn = ((ks + 1) & 15) * 32 + lhi * 8;  // &15: last prefetch stays in-bounds
      half8 nb0 = *(const half8*)(W2h + (n0 + l15) * 512 + kkn);
      half8 nb1 = *(const half8*)(W2h + (n0 + 16 + l15) * 512 + kkn);
      const int kk = ks * 32 + lhi * 8;
#pragma unroll
      for (int mh = 0; mh < 2; ++mh) {
        half8 ax[4];
#pragma unroll
        for (int q = 0; q < 4; ++q) ax[q] = LD_S((mh * 4 + q) * 16 + l15, kk);
#pragma unroll
        for (int q = 0; q < 4; ++q) {
          acc[mh * 4 + q][0] = MFMA16(bw0, ax[q], acc[mh * 4 + q][0], 0, 0, 0);
          acc[mh * 4 + q][1] = MFMA16(bw1, ax[q], acc[mh * 4 + q][1], 0, 0, 0);
        }
      }
      bw0 = nb0; bw1 = nb1;
    }
    __syncthreads();  // all waves done READING S1 before overwrite
#pragma unroll
    for (int nf = 0; nf < 2; ++nf) {
      const int nb = n0 + nf * 16 + lhi * 4;
      const f32x4 bb = *(const f32x4*)(b2 + nb);
#pragma unroll
      for (int mf = 0; mf < 8; ++mf) {
        half4 pk;
#pragma unroll
        for (int r = 0; r < 4; ++r) {
          float h = acc[mf][nf][r] + bb[r];
          h = fminf(fmaxf(h, -25.133f), 25.133f);
          pk[r] = (_Float16)fast_sin(h);
        }
        ST_S8(mf * 16 + l15, nb, pk);
      }
    }
  }
  __syncthreads();

  // ---------------- L3: sin(S @ W3^T + b3) -> out[128,384] fp32 ----------------
  // 24 col-frags over 16 waves: all waves take frag wid; waves 0-7 also 16+wid.
  {
    const int c0 = wid << 4;
    const int c1 = 256 + (wid << 4);
    const bool two = (wid < 8);
    f32x4 acc0[8], acc1[8];
#pragma unroll
    for (int i = 0; i < 8; ++i) { acc0[i] = vzero; acc1[i] = vzero; }
    half8 bw0 = *(const half8*)(W3h + (c0 + l15) * 512 + lhi * 8);
    half8 bw1 = two ? *(const half8*)(W3h + (c1 + l15) * 512 + lhi * 8) : bw0;
#pragma unroll 2
    for (int ks = 0; ks < 16; ++ks) {
      const int kkn = ((ks + 1) & 15) * 32 + lhi * 8;
      half8 nb0 = *(const half8*)(W3h + (c0 + l15) * 512 + kkn);
      half8 nb1 = two ? *(const half8*)(W3h + (c1 + l15) * 512 + kkn) : nb0;
      const int kk = ks * 32 + lhi * 8;
#pragma unroll
      for (int mh = 0; mh < 2; ++mh) {
        half8 ax[4];
#pragma unroll
        for (int q = 0; q < 4; ++q) ax[q] = LD_S((mh * 4 + q) * 16 + l15, kk);
#pragma unroll
        for (int q = 0; q < 4; ++q) {
          acc0[mh * 4 + q] = MFMA16(bw0, ax[q], acc0[mh * 4 + q], 0, 0, 0);
          acc1[mh * 4 + q] = MFMA16(bw1, ax[q], acc1[mh * 4 + q], 0, 0, 0);
        }
      }
      bw0 = nb0; bw1 = nb1;
    }
    {
      const int nb = c0 + lhi * 4;
      const f32x4 bb = *(const f32x4*)(b3 + nb);
#pragma unroll
      for (int mf = 0; mf < 8; ++mf) {
        float4 o;
        float* op = &o.x;
#pragma unroll
        for (int r = 0; r < 4; ++r) {
          float h = acc0[mf][r] + bb[r];
          h = fminf(fmaxf(h, -25.133f), 25.133f);
          op[r] = fast_sin(h);
        }
        *(float4*)(out + (size_t)(pbase + mf * 16 + l15) * 384 + nb) = o;
      }
    }
    if (two) {
      const int nb = c1 + lhi * 4;
      const f32x4 bb = *(const f32x4*)(b3 + nb);
#pragma unroll
      for (int mf = 0; mf < 8; ++mf) {
        float4 o;
        float* op = &o.x;
#pragma unroll
        for (int r = 0; r < 4; ++r) {
          float h = acc1[mf][r] + bb[r];
          h = fminf(fmaxf(h, -25.133f), 25.133f);
          op[r] = fast_sin(h);
        }
        *(float4*)(out + (size_t)(pbase + mf * 16 + l15) * 384 + nb) = o;
      }
    }
  }
}

extern "C" void kernel_launch(void* const* d_in, const int* in_sizes, int n_in,
                              void* d_out, int out_size, void* d_ws, size_t ws_size,
                              hipStream_t stream) {
  const int* y = (const int*)d_in[0];
  const int* x = (const int*)d_in[1];
  const float* cam = (const float*)d_in[2];
  const float* table = (const float*)d_in[3];
  const float* W1 = (const float*)d_in[4];
  const float* b1 = (const float*)d_in[5];
  const float* W2 = (const float*)d_in[6];
  const float* b2 = (const float*)d_in[7];
  const float* W3 = (const float*)d_in[8];
  const float* b3 = (const float*)d_in[9];
  float* out = (float*)d_out;

  _Float16* Wh = (_Float16*)d_ws;      // W1h | W2h | W3h contiguous, 983040 B
  _Float16* W1h = Wh;                  // 512*64
  _Float16* W2h = W1h + 512 * 64;      // 512*512
  _Float16* W3h = W2h + 512 * 512;     // 384*512

  hg_cvt_all<<<480, 256, 0, stream>>>(W1, W2, W3, Wh);

  const int nblocks = (1 << 19) / 128;  // 4096
  hg_fused<<<nblocks, 1024, 0, stream>>>(y, x, cam, table, W1h, b1, W2h, b2, W3h, b3, out);
}